// Round 6
// baseline (831.683 us; speedup 1.0000x reference)
//
#include <hip/hip_runtime.h>

static constexpr int IMG  = 2048;   // H = W
static constexpr int CH   = 3;
static constexpr int KS   = 25;     // PSF size
static constexpr int HALO = 12;     // KS/2
static constexpr int DN   = 512;    // downsampled size (IMG/4)
static constexpr int PD   = 18;     // taps, downsample (kw=16 -> ceil+2)
static constexpr int PU   = 6;      // taps, upsample  (kw=4  -> ceil+2)
static constexpr float LAM = 0.1f;

// ---------------------------------------------------------------------------
// Bicubic resize weight tables (matches MATLAB-style imresize in the ref).
// ---------------------------------------------------------------------------
__device__ __forceinline__ double cubic_d(double x) {
  double ax = fabs(x), ax2 = ax * ax, ax3 = ax2 * ax;
  if (ax <= 1.0) return 1.5 * ax3 - 2.5 * ax2 + 1.0;
  if (ax <= 2.0) return -0.5 * ax3 + 2.5 * ax2 - 4.0 * ax + 2.0;
  return 0.0;
}

__global__ void build_tables(float* dwW, int* dwI, float* uwW, int* uwI) {
  int i = blockIdx.x * blockDim.x + threadIdx.x;
  if (i < DN) {
    const double scale = 0.25;
    double u = (double)(i + 1) / scale + 0.5 * (1.0 - 1.0 / scale);
    double left = floor(u - 8.0);
    double w[PD]; int id[PD]; double s = 0.0;
    for (int p = 0; p < PD; ++p) {
      double ind = left + p;
      w[p] = scale * cubic_d(scale * (u - ind));
      s += w[p];
      long long m = ((long long)ind - 1) % (2 * IMG);
      if (m < 0) m += 2 * IMG;
      id[p] = (m < IMG) ? (int)m : (int)(2 * IMG - 1 - m);
    }
    for (int p = 0; p < PD; ++p) {
      dwW[i * PD + p] = (float)(w[p] / s);
      dwI[i * PD + p] = id[p];
    }
  }
  if (i < IMG) {
    const double scale = 4.0;
    double u = (double)(i + 1) / scale + 0.5 * (1.0 - 1.0 / scale);
    double left = floor(u - 2.0);
    double w[PU]; int id[PU]; double s = 0.0;
    for (int p = 0; p < PU; ++p) {
      double ind = left + p;
      w[p] = cubic_d(u - ind);
      s += w[p];
      long long m = ((long long)ind - 1) % (2 * DN);
      if (m < 0) m += 2 * DN;
      id[p] = (m < DN) ? (int)m : (int)(2 * DN - 1 - m);
    }
    for (int p = 0; p < PU; ++p) {
      uwW[i * PU + p] = (float)(w[p] / s);
      uwI[i * PU + p] = id[p];
    }
  }
}

// ---------------------------------------------------------------------------
// 25x25 circular cross-correlation, fp32.
// FLIP=1: weight = k[24-ky][24-kx], FLIP=0: weight = k[ky][kx].
// Tile: 128x32 outputs / 256 threads; each thread: 8x * 2y outputs.
// LDS: 56x160 (stride 160 == 0 mod 32) + XOR swizzle col ^= ((r>>1)&7)<<2
// -> conflict-free wave64 ds_read_b128 (proven: round-4, 181 us, VALU 80%).
// This round: enforced ping-pong strip prefetch. sched_barrier(0) after each
// LOADSTRIP pins the 8 ds_read_b128 of strip r+1 BEFORE the 400-FMA block of
// strip r (compiler otherwise sinks them to their consumers - round-5 lesson,
// VGPR=88 proved the collapse). Strips 0 and 25 peeled -> guard-free core.
// ---------------------------------------------------------------------------
template <int FLIP>
__global__ __launch_bounds__(256, 4) void corr25(const float* __restrict__ src,
                                                 const float* __restrict__ kwp,
                                                 float* __restrict__ dst) {
  constexpr int TW = 128, TH = 32;
  constexpr int SW = 160;             // padded staged width (152 valid cols)
  constexpr int SH = TH + KS - 1;     // 56
  constexpr int CHUNKS = 152 / 4;     // 38 float4 chunks per staged row
  __shared__ float tile[SH][SW];      // 35840 B -> 4 blocks/CU

  const int tid = threadIdx.x;
  const int c   = blockIdx.z;
  const int x0  = blockIdx.x * TW;
  const int y0  = blockIdx.y * TH;
  const float* s = src + (size_t)c * IMG * IMG;

  // ---- stage (float4 chunks, swizzled writes) ----
  const bool xwrap = (x0 < HALO) || (x0 + TW + HALO > IMG);
  for (int ci = tid; ci < SH * CHUNKS; ci += 256) {
    int r  = ci / CHUNKS;
    int cj = ci - r * CHUNKS;
    int gy = (y0 + r - HALO) & (IMG - 1);
    int col  = 4 * cj;
    int scol = col ^ (((r >> 1) & 7) << 2);
    float4 v;
    if (!xwrap) {
      v = *reinterpret_cast<const float4*>(&s[(size_t)gy * IMG + (x0 - HALO + col)]);
    } else {
      int gx = x0 - HALO + col;
      v.x = s[(size_t)gy * IMG + ((gx + 0) & (IMG - 1))];
      v.y = s[(size_t)gy * IMG + ((gx + 1) & (IMG - 1))];
      v.z = s[(size_t)gy * IMG + ((gx + 2) & (IMG - 1))];
      v.w = s[(size_t)gy * IMG + ((gx + 3) & (IMG - 1))];
    }
    *reinterpret_cast<float4*>(&tile[r][scol]) = v;
  }
  __syncthreads();

  const int tx    = tid & 15;
  const int tyt   = tid >> 4;
  const int ox    = tx * 8;
  const int rbase = tyt * 2;          // this thread's first output row (local)

  float acc0[8], acc1[8];
#pragma unroll
  for (int o = 0; o < 8; ++o) { acc0[o] = 0.f; acc1[o] = 0.f; }

#define LOADSTRIP(BUF, R)                                                     \
  do {                                                                        \
    const int _r   = (R);                                                     \
    const int _swz = ((_r >> 1) & 7) << 2;                                    \
    _Pragma("unroll")                                                         \
    for (int j = 0; j < 8; ++j)                                               \
      BUF[j] = *reinterpret_cast<const float4*>(&tile[_r][(ox + 4 * j) ^ _swz]); \
  } while (0)

#define FMAROW(ACC, BUF, KY)                                                  \
  do {                                                                        \
    const float* _row = reinterpret_cast<const float*>(BUF);                  \
    const int _ky = (KY);                                                     \
    _Pragma("unroll")                                                         \
    for (int kx = 0; kx < KS; ++kx) {                                         \
      float _w = FLIP ? kwp[(KS - 1 - _ky) * KS + (KS - 1 - kx)]              \
                      : kwp[_ky * KS + kx];                                   \
      _Pragma("unroll")                                                       \
      for (int o = 0; o < 8; ++o)                                             \
        ACC[o] = fmaf(_w, _row[kx + o], ACC[o]);                              \
    }                                                                         \
  } while (0)

#define SB() __builtin_amdgcn_sched_barrier(0)

  float4 bufA[8], bufB[8];
  // prologue: strip 0 (acc0 ky=0 only), prefetch strip 1
  LOADSTRIP(bufA, rbase + 0);
  LOADSTRIP(bufB, rbase + 1);
  SB();
  FMAROW(acc0, bufA, 0);

  // steady state: strips 1..24, ping-pong, guard-free
#pragma unroll 1
  for (int rr = 1; rr <= 23; rr += 2) {
    // bufB holds strip rr
    LOADSTRIP(bufA, rbase + rr + 1);
    SB();
    FMAROW(acc0, bufB, rr);
    FMAROW(acc1, bufB, rr - 1);
    // bufA holds strip rr+1
    LOADSTRIP(bufB, rbase + rr + 2);
    SB();
    FMAROW(acc0, bufA, rr + 1);
    FMAROW(acc1, bufA, rr);
  }
  // epilogue: bufB holds strip 25 (acc1 ky=24 only)
  FMAROW(acc1, bufB, 24);

#undef LOADSTRIP
#undef FMAROW
#undef SB

  float* d0 = dst + (size_t)c * IMG * IMG + (size_t)(y0 + rbase) * IMG + x0 + ox;
  *reinterpret_cast<float4*>(d0)           = make_float4(acc0[0], acc0[1], acc0[2], acc0[3]);
  *reinterpret_cast<float4*>(d0 + 4)       = make_float4(acc0[4], acc0[5], acc0[6], acc0[7]);
  *reinterpret_cast<float4*>(d0 + IMG)     = make_float4(acc1[0], acc1[1], acc1[2], acc1[3]);
  *reinterpret_cast<float4*>(d0 + IMG + 4) = make_float4(acc1[4], acc1[5], acc1[6], acc1[7]);
}

// ---------------------------------------------------------------------------
// Separable bicubic resize passes (unchanged)
// ---------------------------------------------------------------------------
__global__ void rows_down(const float* __restrict__ src, float* __restrict__ dst,
                          const float* __restrict__ wW, const int* __restrict__ wI) {
  int x = blockIdx.x * blockDim.x + threadIdx.x;
  int o = blockIdx.y;
  int c = blockIdx.z;
  const float* s = src + (size_t)c * IMG * IMG;
  float acc = 0.f;
#pragma unroll
  for (int p = 0; p < PD; ++p)
    acc = fmaf(wW[o * PD + p], s[(size_t)wI[o * PD + p] * IMG + x], acc);
  dst[((size_t)c * DN + o) * IMG + x] = acc;
}

__global__ void cols_down(const float* __restrict__ src, float* __restrict__ dst,
                          const float* __restrict__ wW, const int* __restrict__ wI) {
  int o = blockIdx.x * blockDim.x + threadIdx.x;
  int y = blockIdx.y;
  int c = blockIdx.z;
  const float* s = src + ((size_t)c * DN + y) * IMG;
  float acc = 0.f;
#pragma unroll
  for (int p = 0; p < PD; ++p)
    acc = fmaf(wW[o * PD + p], s[wI[o * PD + p]], acc);
  dst[((size_t)c * DN + y) * DN + o] = acc;
}

__global__ void rows_up(const float* __restrict__ src, float* __restrict__ dst,
                        const float* __restrict__ wW, const int* __restrict__ wI) {
  int x = blockIdx.x * blockDim.x + threadIdx.x;
  int o = blockIdx.y;
  int c = blockIdx.z;
  const float* s = src + (size_t)c * DN * DN;
  float acc = 0.f;
#pragma unroll
  for (int p = 0; p < PU; ++p)
    acc = fmaf(wW[o * PU + p], s[(size_t)wI[o * PU + p] * DN + x], acc);
  dst[((size_t)c * IMG + o) * DN + x] = acc;
}

__global__ void cols_up_add(const float* __restrict__ src, float* __restrict__ out,
                            const float* __restrict__ wW, const int* __restrict__ wI) {
  int x = blockIdx.x * blockDim.x + threadIdx.x;
  int y = blockIdx.y;
  int c = blockIdx.z;
  const float* s = src + ((size_t)c * IMG + y) * DN;
  float acc = 0.f;
#pragma unroll
  for (int p = 0; p < PU; ++p)
    acc = fmaf(wW[x * PU + p], s[wI[x * PU + p]], acc);
  size_t oi = ((size_t)c * IMG + y) * IMG + x;
  out[oi] = fmaf(LAM, acc, out[oi]);
}

// ---------------------------------------------------------------------------
extern "C" void kernel_launch(void* const* d_in, const int* in_sizes, int n_in,
                              void* d_out, int out_size, void* d_ws, size_t ws_size,
                              hipStream_t stream) {
  const float* im  = (const float*)d_in[0];
  const float* ker = (const float*)d_in[1];
  float* out = (float*)d_out;
  float* ws  = (float*)d_ws;

  const size_t NIM = (size_t)CH * IMG * IMG;

  // ws layout (proven footprint ~50.5 MB):
  //   [0, NIM)   : ax (pass A output) -- later reused for t1/t2/t3
  //   [NIM, ...) : weight tables
  float* ax = ws;
  float* t1 = ws;
  float* t2 = t1 + (size_t)CH * DN * IMG;
  float* t3 = t2 + (size_t)CH * DN * DN;
  float* dwW = ws + NIM;
  int*   dwI = (int*)(dwW + DN * PD);
  float* uwW = (float*)(dwI + DN * PD);
  int*   uwI = (int*)(uwW + (size_t)IMG * PU);

  build_tables<<<(IMG + 255) / 256, 256, 0, stream>>>(dwW, dwI, uwW, uwI);

  // A^T A x: two 25x25 circular correlations (flipped, then plain)
  dim3 cgrid(IMG / 128, IMG / 32, CH);
  corr25<1><<<cgrid, 256, 0, stream>>>(im, ker, ax);
  corr25<0><<<cgrid, 256, 0, stream>>>(ax, ker, out);

  // 0.1 * H^T H x: 4 separable bicubic passes, accumulate into out
  rows_down  <<<dim3(IMG / 256, DN,  CH), 256, 0, stream>>>(im, t1, dwW, dwI);
  cols_down  <<<dim3(DN  / 256, DN,  CH), 256, 0, stream>>>(t1, t2, dwW, dwI);
  rows_up    <<<dim3(DN  / 256, IMG, CH), 256, 0, stream>>>(t2, t3, uwW, uwI);
  cols_up_add<<<dim3(IMG / 256, IMG, CH), 256, 0, stream>>>(t3, out, uwW, uwI);
}

// Round 7
// 489.549 us; speedup vs baseline: 1.6989x; 1.6989x over previous
//
#include <hip/hip_runtime.h>

static constexpr int IMG  = 2048;   // H = W
static constexpr int CH   = 3;
static constexpr int KS   = 25;     // PSF size
static constexpr int HALO = 12;     // KS/2
static constexpr int DN   = 512;    // downsampled size (IMG/4)
static constexpr int PD   = 18;     // taps, downsample (kw=16 -> ceil+2)
static constexpr int PU   = 6;      // taps, upsample  (kw=4  -> ceil+2)
static constexpr float LAM = 0.1f;

// ---------------------------------------------------------------------------
// Bicubic resize weight tables (matches MATLAB-style imresize in the ref).
// ---------------------------------------------------------------------------
__device__ __forceinline__ double cubic_d(double x) {
  double ax = fabs(x), ax2 = ax * ax, ax3 = ax2 * ax;
  if (ax <= 1.0) return 1.5 * ax3 - 2.5 * ax2 + 1.0;
  if (ax <= 2.0) return -0.5 * ax3 + 2.5 * ax2 - 4.0 * ax + 2.0;
  return 0.0;
}

__global__ void build_tables(float* dwW, int* dwI, float* uwW, int* uwI) {
  int i = blockIdx.x * blockDim.x + threadIdx.x;
  if (i < DN) {
    const double scale = 0.25;
    double u = (double)(i + 1) / scale + 0.5 * (1.0 - 1.0 / scale);
    double left = floor(u - 8.0);
    double w[PD]; int id[PD]; double s = 0.0;
    for (int p = 0; p < PD; ++p) {
      double ind = left + p;
      w[p] = scale * cubic_d(scale * (u - ind));
      s += w[p];
      long long m = ((long long)ind - 1) % (2 * IMG);
      if (m < 0) m += 2 * IMG;
      id[p] = (m < IMG) ? (int)m : (int)(2 * IMG - 1 - m);
    }
    for (int p = 0; p < PD; ++p) {
      dwW[i * PD + p] = (float)(w[p] / s);
      dwI[i * PD + p] = id[p];
    }
  }
  if (i < IMG) {
    const double scale = 4.0;
    double u = (double)(i + 1) / scale + 0.5 * (1.0 - 1.0 / scale);
    double left = floor(u - 2.0);
    double w[PU]; int id[PU]; double s = 0.0;
    for (int p = 0; p < PU; ++p) {
      double ind = left + p;
      w[p] = cubic_d(u - ind);
      s += w[p];
      long long m = ((long long)ind - 1) % (2 * DN);
      if (m < 0) m += 2 * DN;
      id[p] = (m < DN) ? (int)m : (int)(2 * DN - 1 - m);
    }
    for (int p = 0; p < PU; ++p) {
      uwW[i * PU + p] = (float)(w[p] / s);
      uwI[i * PU + p] = id[p];
    }
  }
}

// ---------------------------------------------------------------------------
// 25x25 circular cross-correlation, fp32 — PROVEN round-4 config (181 us):
// Tile 128x32 / 256 threads, 8x*2y per thread; LDS 56x160 stride-160 + XOR
// swizzle col ^= ((r>>1)&7)<<2 (conflict-free wave64 ds_read_b128);
// guarded 26-strip loop, #pragma unroll 2. DO NOT add sched_barrier or
// ping-pong buffers: rounds 5/6 proved the compiler collapses (r5, VGPR=88)
// or spills (r6, VGPR=64 + 1.8 GB scratch traffic) them.
// ---------------------------------------------------------------------------
template <int FLIP>
__global__ __launch_bounds__(256, 4) void corr25(const float* __restrict__ src,
                                                 const float* __restrict__ kw,
                                                 float* __restrict__ dst) {
  constexpr int TW = 128, TH = 32;
  constexpr int SW = 160;             // padded staged width (152 valid cols)
  constexpr int SH = TH + KS - 1;     // 56
  constexpr int CHUNKS = 152 / 4;     // 38 float4 chunks per staged row
  __shared__ float tile[SH][SW];      // 35840 B -> 4 blocks/CU

  const int tid = threadIdx.x;
  const int c   = blockIdx.z;
  const int x0  = blockIdx.x * TW;
  const int y0  = blockIdx.y * TH;
  const float* s = src + (size_t)c * IMG * IMG;

  // ---- stage (float4 chunks, swizzled writes) ----
  const bool xwrap = (x0 < HALO) || (x0 + TW + HALO > IMG);
  for (int ci = tid; ci < SH * CHUNKS; ci += 256) {
    int r  = ci / CHUNKS;
    int cj = ci - r * CHUNKS;
    int gy = (y0 + r - HALO) & (IMG - 1);
    int col  = 4 * cj;
    int scol = col ^ (((r >> 1) & 7) << 2);
    float4 v;
    if (!xwrap) {
      v = *reinterpret_cast<const float4*>(&s[(size_t)gy * IMG + (x0 - HALO + col)]);
    } else {
      int gx = x0 - HALO + col;
      v.x = s[(size_t)gy * IMG + ((gx + 0) & (IMG - 1))];
      v.y = s[(size_t)gy * IMG + ((gx + 1) & (IMG - 1))];
      v.z = s[(size_t)gy * IMG + ((gx + 2) & (IMG - 1))];
      v.w = s[(size_t)gy * IMG + ((gx + 3) & (IMG - 1))];
    }
    *reinterpret_cast<float4*>(&tile[r][scol]) = v;
  }
  __syncthreads();

  const int tx    = tid & 15;
  const int tyt   = tid >> 4;
  const int ox    = tx * 8;
  const int rbase = tyt * 2;          // this thread's first output row (local)

  float acc0[8], acc1[8];
#pragma unroll
  for (int o = 0; o < 8; ++o) { acc0[o] = 0.f; acc1[o] = 0.f; }

#pragma unroll 2
  for (int rr = 0; rr < KS + 1; ++rr) {   // 26 staged row-strips per thread
    const int r   = rbase + rr;
    const int swz = ((r >> 1) & 7) << 2;
    float row[32];
#pragma unroll
    for (int j = 0; j < 8; ++j) {
      float4 v = *reinterpret_cast<const float4*>(&tile[r][(ox + 4 * j) ^ swz]);
      row[4 * j + 0] = v.x; row[4 * j + 1] = v.y;
      row[4 * j + 2] = v.z; row[4 * j + 3] = v.w;
    }
    if (rr <= KS - 1) {                 // dy = 0 : ky = rr
      const int ky = rr;
#pragma unroll
      for (int kx = 0; kx < KS; ++kx) {
        float w = FLIP ? kw[(KS - 1 - ky) * KS + (KS - 1 - kx)]
                       : kw[ky * KS + kx];
#pragma unroll
        for (int o = 0; o < 8; ++o) acc0[o] = fmaf(w, row[kx + o], acc0[o]);
      }
    }
    if (rr >= 1) {                      // dy = 1 : ky = rr - 1
      const int ky = rr - 1;
#pragma unroll
      for (int kx = 0; kx < KS; ++kx) {
        float w = FLIP ? kw[(KS - 1 - ky) * KS + (KS - 1 - kx)]
                       : kw[ky * KS + kx];
#pragma unroll
        for (int o = 0; o < 8; ++o) acc1[o] = fmaf(w, row[kx + o], acc1[o]);
      }
    }
  }

  float* d0 = dst + (size_t)c * IMG * IMG + (size_t)(y0 + rbase) * IMG + x0 + ox;
  *reinterpret_cast<float4*>(d0)           = make_float4(acc0[0], acc0[1], acc0[2], acc0[3]);
  *reinterpret_cast<float4*>(d0 + 4)       = make_float4(acc0[4], acc0[5], acc0[6], acc0[7]);
  *reinterpret_cast<float4*>(d0 + IMG)     = make_float4(acc1[0], acc1[1], acc1[2], acc1[3]);
  *reinterpret_cast<float4*>(d0 + IMG + 4) = make_float4(acc1[4], acc1[5], acc1[6], acc1[7]);
}

// ---------------------------------------------------------------------------
// A/B variant for pass B: identical geometry, but strips 0 and 25 peeled so
// the 24-iteration core is branch-free (no row guards). Single row buffer,
// NO sched_barrier, NO ping-pong — compiler schedules freely.
// ---------------------------------------------------------------------------
template <int FLIP>
__global__ __launch_bounds__(256, 4) void corr25b(const float* __restrict__ src,
                                                  const float* __restrict__ kw,
                                                  float* __restrict__ dst) {
  constexpr int TW = 128, TH = 32;
  constexpr int SW = 160;
  constexpr int SH = TH + KS - 1;     // 56
  constexpr int CHUNKS = 152 / 4;     // 38
  __shared__ float tile[SH][SW];

  const int tid = threadIdx.x;
  const int c   = blockIdx.z;
  const int x0  = blockIdx.x * TW;
  const int y0  = blockIdx.y * TH;
  const float* s = src + (size_t)c * IMG * IMG;

  const bool xwrap = (x0 < HALO) || (x0 + TW + HALO > IMG);
  for (int ci = tid; ci < SH * CHUNKS; ci += 256) {
    int r  = ci / CHUNKS;
    int cj = ci - r * CHUNKS;
    int gy = (y0 + r - HALO) & (IMG - 1);
    int col  = 4 * cj;
    int scol = col ^ (((r >> 1) & 7) << 2);
    float4 v;
    if (!xwrap) {
      v = *reinterpret_cast<const float4*>(&s[(size_t)gy * IMG + (x0 - HALO + col)]);
    } else {
      int gx = x0 - HALO + col;
      v.x = s[(size_t)gy * IMG + ((gx + 0) & (IMG - 1))];
      v.y = s[(size_t)gy * IMG + ((gx + 1) & (IMG - 1))];
      v.z = s[(size_t)gy * IMG + ((gx + 2) & (IMG - 1))];
      v.w = s[(size_t)gy * IMG + ((gx + 3) & (IMG - 1))];
    }
    *reinterpret_cast<float4*>(&tile[r][scol]) = v;
  }
  __syncthreads();

  const int tx    = tid & 15;
  const int tyt   = tid >> 4;
  const int ox    = tx * 8;
  const int rbase = tyt * 2;

  float acc0[8], acc1[8];
#pragma unroll
  for (int o = 0; o < 8; ++o) { acc0[o] = 0.f; acc1[o] = 0.f; }

#define LOADROW(R)                                                            \
  do {                                                                        \
    const int _r   = (R);                                                     \
    const int _swz = ((_r >> 1) & 7) << 2;                                    \
    _Pragma("unroll")                                                         \
    for (int j = 0; j < 8; ++j) {                                             \
      float4 v = *reinterpret_cast<const float4*>(&tile[_r][(ox + 4 * j) ^ _swz]); \
      row[4 * j + 0] = v.x; row[4 * j + 1] = v.y;                             \
      row[4 * j + 2] = v.z; row[4 * j + 3] = v.w;                             \
    }                                                                         \
  } while (0)

#define FMAROW(ACC, KY)                                                       \
  do {                                                                        \
    const int _ky = (KY);                                                     \
    _Pragma("unroll")                                                         \
    for (int kx = 0; kx < KS; ++kx) {                                         \
      float _w = FLIP ? kw[(KS - 1 - _ky) * KS + (KS - 1 - kx)]               \
                      : kw[_ky * KS + kx];                                    \
      _Pragma("unroll")                                                       \
      for (int o = 0; o < 8; ++o)                                             \
        ACC[o] = fmaf(_w, row[kx + o], ACC[o]);                               \
    }                                                                         \
  } while (0)

  float row[32];
  // peel strip 0: contributes only acc0 (ky = 0)
  LOADROW(rbase);
  FMAROW(acc0, 0);
  // branch-free core: strips 1..24 contribute acc0 (ky=rr) and acc1 (ky=rr-1)
#pragma unroll 2
  for (int rr = 1; rr <= 24; ++rr) {
    LOADROW(rbase + rr);
    FMAROW(acc0, rr);
    FMAROW(acc1, rr - 1);
  }
  // peel strip 25: contributes only acc1 (ky = 24)
  LOADROW(rbase + 25);
  FMAROW(acc1, 24);

#undef LOADROW
#undef FMAROW

  float* d0 = dst + (size_t)c * IMG * IMG + (size_t)(y0 + rbase) * IMG + x0 + ox;
  *reinterpret_cast<float4*>(d0)           = make_float4(acc0[0], acc0[1], acc0[2], acc0[3]);
  *reinterpret_cast<float4*>(d0 + 4)       = make_float4(acc0[4], acc0[5], acc0[6], acc0[7]);
  *reinterpret_cast<float4*>(d0 + IMG)     = make_float4(acc1[0], acc1[1], acc1[2], acc1[3]);
  *reinterpret_cast<float4*>(d0 + IMG + 4) = make_float4(acc1[4], acc1[5], acc1[6], acc1[7]);
}

// ---------------------------------------------------------------------------
// Downsample passes (unchanged, proven)
// ---------------------------------------------------------------------------
__global__ void rows_down(const float* __restrict__ src, float* __restrict__ dst,
                          const float* __restrict__ wW, const int* __restrict__ wI) {
  int x = blockIdx.x * blockDim.x + threadIdx.x;
  int o = blockIdx.y;
  int c = blockIdx.z;
  const float* s = src + (size_t)c * IMG * IMG;
  float acc = 0.f;
#pragma unroll
  for (int p = 0; p < PD; ++p)
    acc = fmaf(wW[o * PD + p], s[(size_t)wI[o * PD + p] * IMG + x], acc);
  dst[((size_t)c * DN + o) * IMG + x] = acc;
}

__global__ void cols_down(const float* __restrict__ src, float* __restrict__ dst,
                          const float* __restrict__ wW, const int* __restrict__ wI) {
  int o = blockIdx.x * blockDim.x + threadIdx.x;
  int y = blockIdx.y;
  int c = blockIdx.z;
  const float* s = src + ((size_t)c * DN + y) * IMG;
  float acc = 0.f;
#pragma unroll
  for (int p = 0; p < PD; ++p)
    acc = fmaf(wW[o * PD + p], s[wI[o * PD + p]], acc);
  dst[((size_t)c * DN + y) * DN + o] = acc;
}

// ---------------------------------------------------------------------------
// Fused upsample (rows_up + cols_up_add): out += LAM * up4(t2).
// Per output: 6x6 separable gathers from L2-resident t2 (1 MB/channel).
// Replaces the t3 (C,2048,512) 100 MB round-trip and one launch.
// ---------------------------------------------------------------------------
__global__ void upfuse_add(const float* __restrict__ t2, float* __restrict__ out,
                           const float* __restrict__ wW, const int* __restrict__ wI) {
  int x = blockIdx.x * blockDim.x + threadIdx.x;  // 0..2047
  int y = blockIdx.y;                             // 0..2047
  int c = blockIdx.z;
  const float* T = t2 + (size_t)c * DN * DN;

  float wq[PU]; int xq[PU];
#pragma unroll
  for (int q = 0; q < PU; ++q) {
    wq[q] = wW[x * PU + q];
    xq[q] = wI[x * PU + q];
  }
  float acc = 0.f;
#pragma unroll
  for (int p = 0; p < PU; ++p) {
    const float  wp = wW[y * PU + p];       // uniform over block -> scalar
    const float* R  = T + (size_t)wI[y * PU + p] * DN;
    float rs = 0.f;
#pragma unroll
    for (int q = 0; q < PU; ++q) rs = fmaf(wq[q], R[xq[q]], rs);
    acc = fmaf(wp, rs, acc);
  }
  size_t oi = ((size_t)c * IMG + y) * IMG + x;
  out[oi] = fmaf(LAM, acc, out[oi]);
}

// ---------------------------------------------------------------------------
extern "C" void kernel_launch(void* const* d_in, const int* in_sizes, int n_in,
                              void* d_out, int out_size, void* d_ws, size_t ws_size,
                              hipStream_t stream) {
  const float* im  = (const float*)d_in[0];
  const float* ker = (const float*)d_in[1];
  float* out = (float*)d_out;
  float* ws  = (float*)d_ws;

  const size_t NIM = (size_t)CH * IMG * IMG;

  // ws layout:
  //   [0, NIM)   : ax (pass A output) -- later reused for t1/t2
  //   [NIM, ...) : weight tables
  float* ax = ws;
  float* t1 = ws;                              // overwrites ax (after pass B)
  float* t2 = t1 + (size_t)CH * DN * IMG;
  float* dwW = ws + NIM;
  int*   dwI = (int*)(dwW + DN * PD);
  float* uwW = (float*)(dwI + DN * PD);
  int*   uwI = (int*)(uwW + (size_t)IMG * PU);

  build_tables<<<(IMG + 255) / 256, 256, 0, stream>>>(dwW, dwI, uwW, uwI);

  // A^T A x: two 25x25 circular correlations. Pass A = proven round-4 config;
  // pass B = branchless-peeled A/B variant (per-dispatch counters compare).
  dim3 cgrid(IMG / 128, IMG / 32, CH);
  corr25 <1><<<cgrid, 256, 0, stream>>>(im, ker, ax);
  corr25b<0><<<cgrid, 256, 0, stream>>>(ax, ker, out);

  // 0.1 * H^T H x: downsample to t2, then fused upsample-accumulate.
  rows_down <<<dim3(IMG / 256, DN,  CH), 256, 0, stream>>>(im, t1, dwW, dwI);
  cols_down <<<dim3(DN  / 256, DN,  CH), 256, 0, stream>>>(t1, t2, dwW, dwI);
  upfuse_add<<<dim3(IMG / 256, IMG, CH), 256, 0, stream>>>(t2, out, uwW, uwI);
}

// Round 8
// 463.627 us; speedup vs baseline: 1.7939x; 1.0559x over previous
//
#include <hip/hip_runtime.h>

static constexpr int IMG  = 2048;   // H = W
static constexpr int CH   = 3;
static constexpr int KS   = 25;     // PSF size
static constexpr int HALO = 12;     // KS/2
static constexpr int DN   = 512;    // downsampled size (IMG/4)
static constexpr int PD   = 18;     // taps, downsample (kw=16 -> ceil+2)
static constexpr int PU   = 6;      // taps, upsample  (kw=4  -> ceil+2)
static constexpr float LAM = 0.1f;

// ---------------------------------------------------------------------------
// Bicubic resize weight tables (matches MATLAB-style imresize in the ref).
// ---------------------------------------------------------------------------
__device__ __forceinline__ double cubic_d(double x) {
  double ax = fabs(x), ax2 = ax * ax, ax3 = ax2 * ax;
  if (ax <= 1.0) return 1.5 * ax3 - 2.5 * ax2 + 1.0;
  if (ax <= 2.0) return -0.5 * ax3 + 2.5 * ax2 - 4.0 * ax + 2.0;
  return 0.0;
}

__global__ void build_tables(float* dwW, int* dwI, float* uwW, int* uwI) {
  int i = blockIdx.x * blockDim.x + threadIdx.x;
  if (i < DN) {
    const double scale = 0.25;
    double u = (double)(i + 1) / scale + 0.5 * (1.0 - 1.0 / scale);
    double left = floor(u - 8.0);
    double w[PD]; int id[PD]; double s = 0.0;
    for (int p = 0; p < PD; ++p) {
      double ind = left + p;
      w[p] = scale * cubic_d(scale * (u - ind));
      s += w[p];
      long long m = ((long long)ind - 1) % (2 * IMG);
      if (m < 0) m += 2 * IMG;
      id[p] = (m < IMG) ? (int)m : (int)(2 * IMG - 1 - m);
    }
    for (int p = 0; p < PD; ++p) {
      dwW[i * PD + p] = (float)(w[p] / s);
      dwI[i * PD + p] = id[p];
    }
  }
  if (i < IMG) {
    const double scale = 4.0;
    double u = (double)(i + 1) / scale + 0.5 * (1.0 - 1.0 / scale);
    double left = floor(u - 2.0);
    double w[PU]; int id[PU]; double s = 0.0;
    for (int p = 0; p < PU; ++p) {
      double ind = left + p;
      w[p] = cubic_d(u - ind);
      s += w[p];
      long long m = ((long long)ind - 1) % (2 * DN);
      if (m < 0) m += 2 * DN;
      id[p] = (m < DN) ? (int)m : (int)(2 * DN - 1 - m);
    }
    for (int p = 0; p < PU; ++p) {
      uwW[i * PU + p] = (float)(w[p] / s);
      uwI[i * PU + p] = id[p];
    }
  }
}

// ---------------------------------------------------------------------------
// 25x25 circular cross-correlation, fp32 — PROVEN round-4 compute config:
// Tile 128x32 / 256 threads, 8x*2y per thread; LDS 56x160 stride-160 + XOR
// swizzle col ^= ((r>>1)&7)<<2 (conflict-free wave64 ds_read_b128); guarded
// 26-strip loop, #pragma unroll 2. DO NOT add sched_barrier / ping-pong
// (r5: compiler collapses them, VGPR=88; r6: spills, 1.8 GB scratch traffic).
// NEW (r8): staging via __builtin_amdgcn_global_load_lds width=16 for the
// 14/16 non-x-wrap block columns. LDS dest is wave-uniform (linear chunks);
// the swizzle is applied by pre-inverse-swizzling the per-lane GLOBAL source
// (rule: linear dest + inverse-swz source == swz on read). 16-B lane loads
// never cross the 640-B row stride; pad slots get in-bounds junk, never read.
// ---------------------------------------------------------------------------
template <int FLIP>
__global__ __launch_bounds__(256, 4) void corr25(const float* __restrict__ src,
                                                 const float* __restrict__ kw,
                                                 float* __restrict__ dst) {
  constexpr int TW = 128, TH = 32;
  constexpr int SW = 160;             // padded staged width (152 valid cols)
  constexpr int SH = TH + KS - 1;     // 56
  constexpr int CHUNKS = 152 / 4;     // 38 float4 chunks per staged row
  constexpr int NBYTES = SH * SW * 4; // 35840 = 35 * 1024
  __shared__ float tile[SH][SW];      // 35840 B -> 4 blocks/CU

  const int tid = threadIdx.x;
  const int c   = blockIdx.z;
  const int x0  = blockIdx.x * TW;
  const int y0  = blockIdx.y * TH;
  const float* s = src + (size_t)c * IMG * IMG;

  const bool xwrap = (x0 < HALO) || (x0 + TW + HALO > IMG);
  if (!xwrap) {
    // ---- fast path: async global->LDS, 1024-B wave-uniform chunks ----
    const int wid  = tid >> 6;        // 0..3
    const int lane = tid & 63;
    int byte0 = wid * 1024 + lane * 16;
    int r = byte0 / 640;              // row within tile
    int b = byte0 - r * 640;          // 16-aligned byte within row
#pragma unroll 1
    for (int k = wid; k < NBYTES / 1024; k += 4) {
      int gy = (y0 + r - HALO) & (IMG - 1);
      int cb = b ^ (((r >> 1) & 7) << 4);   // inverse-swizzled byte-in-row
      const float* grow = s + (size_t)gy * IMG + (x0 - HALO);
      const char*  gsrc = (const char*)grow + cb;
      char* ldst = (char*)(&tile[0][0]) + (size_t)k * 1024;  // wave-uniform
      __builtin_amdgcn_global_load_lds(
          (const __attribute__((address_space(1))) uint32_t*)gsrc,
          (__attribute__((address_space(3))) uint32_t*)ldst, 16, 0, 0);
      r += 6; b += 256;               // advance 4096 B (= 6*640 + 256)
      if (b >= 640) { b -= 640; ++r; }
    }
  } else {
    // ---- wrap path (blockIdx.x == 0 or 15): scalar wrap loads ----
    for (int ci = tid; ci < SH * CHUNKS; ci += 256) {
      int r  = ci / CHUNKS;
      int cj = ci - r * CHUNKS;
      int gy = (y0 + r - HALO) & (IMG - 1);
      int col  = 4 * cj;
      int scol = col ^ (((r >> 1) & 7) << 2);
      int gx = x0 - HALO + col;
      float4 v;
      v.x = s[(size_t)gy * IMG + ((gx + 0) & (IMG - 1))];
      v.y = s[(size_t)gy * IMG + ((gx + 1) & (IMG - 1))];
      v.z = s[(size_t)gy * IMG + ((gx + 2) & (IMG - 1))];
      v.w = s[(size_t)gy * IMG + ((gx + 3) & (IMG - 1))];
      *reinterpret_cast<float4*>(&tile[r][scol]) = v;
    }
  }
  __syncthreads();

  const int tx    = tid & 15;
  const int tyt   = tid >> 4;
  const int ox    = tx * 8;
  const int rbase = tyt * 2;          // this thread's first output row (local)

  float acc0[8], acc1[8];
#pragma unroll
  for (int o = 0; o < 8; ++o) { acc0[o] = 0.f; acc1[o] = 0.f; }

#pragma unroll 2
  for (int rr = 0; rr < KS + 1; ++rr) {   // 26 staged row-strips per thread
    const int r   = rbase + rr;
    const int swz = ((r >> 1) & 7) << 2;
    float row[32];
#pragma unroll
    for (int j = 0; j < 8; ++j) {
      float4 v = *reinterpret_cast<const float4*>(&tile[r][(ox + 4 * j) ^ swz]);
      row[4 * j + 0] = v.x; row[4 * j + 1] = v.y;
      row[4 * j + 2] = v.z; row[4 * j + 3] = v.w;
    }
    if (rr <= KS - 1) {                 // dy = 0 : ky = rr
      const int ky = rr;
#pragma unroll
      for (int kx = 0; kx < KS; ++kx) {
        float w = FLIP ? kw[(KS - 1 - ky) * KS + (KS - 1 - kx)]
                       : kw[ky * KS + kx];
#pragma unroll
        for (int o = 0; o < 8; ++o) acc0[o] = fmaf(w, row[kx + o], acc0[o]);
      }
    }
    if (rr >= 1) {                      // dy = 1 : ky = rr - 1
      const int ky = rr - 1;
#pragma unroll
      for (int kx = 0; kx < KS; ++kx) {
        float w = FLIP ? kw[(KS - 1 - ky) * KS + (KS - 1 - kx)]
                       : kw[ky * KS + kx];
#pragma unroll
        for (int o = 0; o < 8; ++o) acc1[o] = fmaf(w, row[kx + o], acc1[o]);
      }
    }
  }

  float* d0 = dst + (size_t)c * IMG * IMG + (size_t)(y0 + rbase) * IMG + x0 + ox;
  *reinterpret_cast<float4*>(d0)           = make_float4(acc0[0], acc0[1], acc0[2], acc0[3]);
  *reinterpret_cast<float4*>(d0 + 4)       = make_float4(acc0[4], acc0[5], acc0[6], acc0[7]);
  *reinterpret_cast<float4*>(d0 + IMG)     = make_float4(acc1[0], acc1[1], acc1[2], acc1[3]);
  *reinterpret_cast<float4*>(d0 + IMG + 4) = make_float4(acc1[4], acc1[5], acc1[6], acc1[7]);
}

// ---------------------------------------------------------------------------
// Separable bicubic resize passes (round-4 proven tail, ~109 us total;
// r7 proved the gather-fused upsample is SLOWER — keep separable)
// ---------------------------------------------------------------------------
__global__ void rows_down(const float* __restrict__ src, float* __restrict__ dst,
                          const float* __restrict__ wW, const int* __restrict__ wI) {
  int x = blockIdx.x * blockDim.x + threadIdx.x;
  int o = blockIdx.y;
  int c = blockIdx.z;
  const float* s = src + (size_t)c * IMG * IMG;
  float acc = 0.f;
#pragma unroll
  for (int p = 0; p < PD; ++p)
    acc = fmaf(wW[o * PD + p], s[(size_t)wI[o * PD + p] * IMG + x], acc);
  dst[((size_t)c * DN + o) * IMG + x] = acc;
}

__global__ void cols_down(const float* __restrict__ src, float* __restrict__ dst,
                          const float* __restrict__ wW, const int* __restrict__ wI) {
  int o = blockIdx.x * blockDim.x + threadIdx.x;
  int y = blockIdx.y;
  int c = blockIdx.z;
  const float* s = src + ((size_t)c * DN + y) * IMG;
  float acc = 0.f;
#pragma unroll
  for (int p = 0; p < PD; ++p)
    acc = fmaf(wW[o * PD + p], s[wI[o * PD + p]], acc);
  dst[((size_t)c * DN + y) * DN + o] = acc;
}

__global__ void rows_up(const float* __restrict__ src, float* __restrict__ dst,
                        const float* __restrict__ wW, const int* __restrict__ wI) {
  int x = blockIdx.x * blockDim.x + threadIdx.x;
  int o = blockIdx.y;
  int c = blockIdx.z;
  const float* s = src + (size_t)c * DN * DN;
  float acc = 0.f;
#pragma unroll
  for (int p = 0; p < PU; ++p)
    acc = fmaf(wW[o * PU + p], s[(size_t)wI[o * PU + p] * DN + x], acc);
  dst[((size_t)c * IMG + o) * DN + x] = acc;
}

__global__ void cols_up_add(const float* __restrict__ src, float* __restrict__ out,
                            const float* __restrict__ wW, const int* __restrict__ wI) {
  int x = blockIdx.x * blockDim.x + threadIdx.x;
  int y = blockIdx.y;
  int c = blockIdx.z;
  const float* s = src + ((size_t)c * IMG + y) * DN;
  float acc = 0.f;
#pragma unroll
  for (int p = 0; p < PU; ++p)
    acc = fmaf(wW[x * PU + p], s[wI[x * PU + p]], acc);
  size_t oi = ((size_t)c * IMG + y) * IMG + x;
  out[oi] = fmaf(LAM, acc, out[oi]);
}

// ---------------------------------------------------------------------------
extern "C" void kernel_launch(void* const* d_in, const int* in_sizes, int n_in,
                              void* d_out, int out_size, void* d_ws, size_t ws_size,
                              hipStream_t stream) {
  const float* im  = (const float*)d_in[0];
  const float* ker = (const float*)d_in[1];
  float* out = (float*)d_out;
  float* ws  = (float*)d_ws;

  const size_t NIM = (size_t)CH * IMG * IMG;

  // ws layout (round-4 proven):
  //   [0, NIM)   : ax (pass A output) -- later reused for t1/t2/t3
  //   [NIM, ...) : weight tables
  float* ax = ws;
  float* t1 = ws;
  float* t2 = t1 + (size_t)CH * DN * IMG;
  float* t3 = t2 + (size_t)CH * DN * DN;
  float* dwW = ws + NIM;
  int*   dwI = (int*)(dwW + DN * PD);
  float* uwW = (float*)(dwI + DN * PD);
  int*   uwI = (int*)(uwW + (size_t)IMG * PU);

  build_tables<<<(IMG + 255) / 256, 256, 0, stream>>>(dwW, dwI, uwW, uwI);

  // A^T A x: two 25x25 circular correlations (flipped, then plain)
  dim3 cgrid(IMG / 128, IMG / 32, CH);
  corr25<1><<<cgrid, 256, 0, stream>>>(im, ker, ax);
  corr25<0><<<cgrid, 256, 0, stream>>>(ax, ker, out);

  // 0.1 * H^T H x: 4 separable bicubic passes, accumulate into out
  rows_down  <<<dim3(IMG / 256, DN,  CH), 256, 0, stream>>>(im, t1, dwW, dwI);
  cols_down  <<<dim3(DN  / 256, DN,  CH), 256, 0, stream>>>(t1, t2, dwW, dwI);
  rows_up    <<<dim3(DN  / 256, IMG, CH), 256, 0, stream>>>(t2, t3, uwW, uwI);
  cols_up_add<<<dim3(IMG / 256, IMG, CH), 256, 0, stream>>>(t3, out, uwW, uwI);
}